// Round 1
// baseline (25.947 us; speedup 1.0000x reference)
//
#include <hip/hip_runtime.h>

// out[b][i][j][k] = ah[b][i] * vh[b][j] * th[b][k], with ah/vh/th = [1, row].
// B=128, D=63 -> padded dim 64. Output flat layout: (((b*64)+i)*64+j)*64+k.
// Pure store-bandwidth-bound: 134 MB fp32 out, ~96 KB in.

__global__ __launch_bounds__(256) void tensorFusion_kernel(
    const float* __restrict__ t,
    const float* __restrict__ a,
    const float* __restrict__ v,
    float* __restrict__ out)
{
    const int D = 63;
    const int bi = blockIdx.x;   // b*64 + i
    const int b  = bi >> 6;
    const int i  = bi & 63;

    __shared__ float vh[64];
    __shared__ float th[64];

    const int tid = threadIdx.x;
    if (tid < 64) {
        vh[tid] = (tid == 0) ? 1.0f : v[b * D + (tid - 1)];
        th[tid] = (tid == 0) ? 1.0f : t[b * D + (tid - 1)];
    }
    const float ai = (i == 0) ? 1.0f : a[b * D + (i - 1)];
    __syncthreads();

    // This block owns a contiguous 4096-float slab: out + bi*4096.
    float4* __restrict__ outp = reinterpret_cast<float4*>(out + (size_t)bi * 4096);

    #pragma unroll
    for (int pass = 0; pass < 4; ++pass) {
        const int idx = pass * 256 + tid;  // float4 index within slab, 0..1023
        const int off = idx << 2;          // float offset, multiple of 4
        const int j   = off >> 6;          // 0..63
        const int k   = off & 63;          // 0,4,...,60 (never crosses j)
        const float s = ai * vh[j];
        float4 r;
        r.x = s * th[k + 0];
        r.y = s * th[k + 1];
        r.z = s * th[k + 2];
        r.w = s * th[k + 3];
        outp[idx] = r;
    }
}

extern "C" void kernel_launch(void* const* d_in, const int* in_sizes, int n_in,
                              void* d_out, int out_size, void* d_ws, size_t ws_size,
                              hipStream_t stream) {
    const float* t = (const float*)d_in[0];
    const float* a = (const float*)d_in[1];
    const float* v = (const float*)d_in[2];
    float* out = (float*)d_out;

    // 128 batches * 64 i-values = 8192 blocks, each writes 64*64 floats.
    tensorFusion_kernel<<<dim3(128 * 64), dim3(256), 0, stream>>>(t, a, v, out);
}